// Round 18
// baseline (534.544 us; speedup 1.0000x reference)
//
#include <hip/hip_runtime.h>
#include <math.h>

#define NN 50000
#define EE 800000
#define EEN (EE+NN)          // edges + self loops
#define STRIDE 64            // fixed CSR stride: self + up to 63 in-edges
#define NFEAT 4
#define EFEAT 4
#define EMBD 16
#define IN0 20   // NF + EMB
#define HIDD 64
#define OUTD 128
#define ZB 16                // zred buckets per head (atomic spread)

// bf16 helpers: storage = unsigned short, RTN-even pack, shift-decode
__device__ __forceinline__ unsigned short f2bf(float f){
  unsigned u = __float_as_uint(f);
  return (unsigned short)((u + 0x7FFFu + ((u>>16)&1u)) >> 16);
}
__device__ __forceinline__ float bfl(unsigned u){ return __uint_as_float(u<<16); }
__device__ __forceinline__ float bfh(unsigned u){ return __uint_as_float(u & 0xFFFF0000u); }

// fp16 helpers (RNE via _Float16 cast). fp16 is SAFE for p (max ~1e5 < 65504,
// R12 measured absmax identical to f32-p). fp8 is NOT (p tails > 448 -> NaN
// from unclamped v_cvt_pk_fp8_f32; R14 failure).
__device__ __forceinline__ unsigned f2h2(float a, float b){
  _Float16 ha=(_Float16)a, hb=(_Float16)b;
  unsigned short ua=*(unsigned short*)&ha, ub=*(unsigned short*)&hb;
  return (unsigned)ua | ((unsigned)ub<<16);
}
__device__ __forceinline__ float h2f(unsigned short u){
  _Float16 h=*(_Float16*)&u; return (float)h;
}

// ext_vector types for nontemporal builtins (HIP uint4 is a struct, not ok)
typedef unsigned uv4 __attribute__((ext_vector_type(4)));
typedef unsigned uv2 __attribute__((ext_vector_type(2)));
template<typename T>
__device__ __forceinline__ T ntload(const T* p){
  return __builtin_nontemporal_load(const_cast<T*>(p));
}

template<int V> struct ldt;
template<> struct ldt<4>{ using T = uint2; };
template<> struct ldt<2>{ using T = unsigned int; };

// ---------------- av (all 3 layers) + zred init + fill zero, one launch ----
template<int F_IN,int HH,int CC>
__device__ __forceinline__ void av_one(const float* W, const float* asrc,
                                       const float* adst, float* av, int tid){
  if (tid >= HH*F_IN) return;
  int h = tid / F_IN, f = tid % F_IN;
  float s1=0.f, s2=0.f;
  for (int c=0;c<CC;c++){
    float wv = W[(size_t)(h*CC+c)*F_IN+f];
    s1 += asrc[h*CC+c]*wv;
    s2 += adst[h*CC+c]*wv;
  }
  av[tid] = s1;
  av[HH*F_IN+tid] = s2;
}
// zred layout: per layer, 4 heads x 16 buckets x 16 floats — each bucket on
// its OWN 64B line. 50k atomics / 64 lines = 781/line ~ 2.3us at the
// measured ~3ns/op same-line rate, overlapped under k_edge2.
// Layer l head h bucket b at zred[l*1024 + h*256 + b*16].
__global__ void k_av3(const float* W0, const float* as0, const float* ad0, float* av0,
                      const float* W1, const float* as1, const float* ad1, float* av1,
                      const float* W2, const float* as2, const float* ad2, float* av2,
                      float* zred, int* fill){
  int b = blockIdx.x, tid = threadIdx.x;
  if (b < 3){
    for (int i=tid; i<1024; i+=256) zred[b*1024+i]=0.f;
    if      (b==0) av_one<IN0,4,64> (W0, as0, ad0, av0, tid);
    else if (b==1) av_one<64,4,64>  (W1, as1, ad1, av1, tid);
    else           av_one<64,1,128> (W2, as2, ad2, av2, tid);
  } else {
    int i=(b-3)*256+tid; if (i<NN) fill[i]=0;
  }
}

// ---------------- fixed-stride CSR scatter, 16B packed records ----------
// erec[slot] = {src, eattr(4x fp16), pad}: ONE 16B random store to ONE line
// per edge. Self loop at slot n*64: {src=n, ea=0}.
__global__ void k_scatter(const int* __restrict__ ei, const float4* __restrict__ eattr,
                          int* fill, uv4* __restrict__ erec){
  int idx = blockIdx.x*blockDim.x + threadIdx.x;
  if (idx < EE){
    int d = ei[EE+idx];
    int s = ei[idx];
    float4 ea = eattr[idx];
    int pos = atomicAdd(&fill[d],1);
    int slot = d*STRIDE + 1 + pos;
    uv4 r; r.x=(unsigned)s; r.y=f2h2(ea.x,ea.y); r.z=f2h2(ea.z,ea.w); r.w=0u;
    erec[slot]=r;
  } else if (idx < EEN){
    int n = idx-EE;
    uv4 r; r.x=(unsigned)n; r.y=0u; r.z=0u; r.w=0u;
    erec[n*STRIDE]=r;
  }
}

// ---------------- outer-product register-tiled GEMM + fused scores --------
template<int K,int NCOL,int HH,bool CONCAT>
__global__ __launch_bounds__(256)
void k_gemm(const float* __restrict__ xin, const int* __restrict__ jt,
            const float* __restrict__ emb, const float* __restrict__ W,
            const float* __restrict__ avp, unsigned short* __restrict__ hout,
            float* __restrict__ si, float* __restrict__ sj){
  constexpr int PITCH = 132;
  __shared__ float xT[K*PITCH];
  __shared__ float wT[K*PITCH];
  __shared__ float EMBL[CONCAT ? 17*EMBD : 1];
  int tid = threadIdx.x;
  int rbase = blockIdx.x*128, cbase = blockIdx.y*128;
  if (CONCAT){
    for (int i=tid; i<17*EMBD; i+=256) EMBL[i]=emb[i];
    __syncthreads();
    if (tid < 128){
      int row = tid;
      int gr = rbase+row; if (gr >= NN) gr = NN-1;
      float4 v = ((const float4*)xin)[gr];
      xT[0*PITCH+row]=v.x; xT[1*PITCH+row]=v.y;
      xT[2*PITCH+row]=v.z; xT[3*PITCH+row]=v.w;
      int j = jt[gr];
      #pragma unroll
      for (int k=0;k<EMBD;k++) xT[(NFEAT+k)*PITCH+row] = EMBL[j*EMBD+k];
    } else {
      int col = tid-128;
      const float4* wp = (const float4*)(W + (size_t)(cbase+col)*K);
      #pragma unroll
      for (int k4=0;k4<K/4;k4++){
        float4 v = wp[k4];
        wT[(4*k4+0)*PITCH+col]=v.x; wT[(4*k4+1)*PITCH+col]=v.y;
        wT[(4*k4+2)*PITCH+col]=v.z; wT[(4*k4+3)*PITCH+col]=v.w;
      }
    }
  } else {
    constexpr int K4 = K/4;
    for (int i=tid; i<128*K4; i+=256){
      int row = i/K4, k4 = i%K4;
      int gr = rbase+row; if (gr >= NN) gr = NN-1;
      float4 v = ((const float4*)xin)[(size_t)gr*K4 + k4];
      xT[(4*k4+0)*PITCH+row]=v.x; xT[(4*k4+1)*PITCH+row]=v.y;
      xT[(4*k4+2)*PITCH+row]=v.z; xT[(4*k4+3)*PITCH+row]=v.w;
    }
    for (int i=tid; i<128*K4; i+=256){
      int col = i/K4, k4 = i%K4;
      float4 v = ((const float4*)W)[(size_t)(cbase+col)*K4 + k4];
      wT[(4*k4+0)*PITCH+col]=v.x; wT[(4*k4+1)*PITCH+col]=v.y;
      wT[(4*k4+2)*PITCH+col]=v.z; wT[(4*k4+3)*PITCH+col]=v.w;
    }
  }
  __syncthreads();
  int lane = tid & 63, w = tid >> 6;
  int r0 = (w>>1)*64 + (lane&7)*8;
  int c0 = (w&1)*64 + (lane>>3)*8;
  float acc[8][8];
  #pragma unroll
  for (int i=0;i<8;i++)
    #pragma unroll
    for (int j=0;j<8;j++) acc[i][j]=0.f;
  #pragma unroll 4
  for (int k=0;k<K;k++){
    float a[8], b[8];
    *(float4*)&a[0] = *(const float4*)&xT[k*PITCH + r0];
    *(float4*)&a[4] = *(const float4*)&xT[k*PITCH + r0 + 4];
    *(float4*)&b[0] = *(const float4*)&wT[k*PITCH + c0];
    *(float4*)&b[4] = *(const float4*)&wT[k*PITCH + c0 + 4];
    #pragma unroll
    for (int i=0;i<8;i++)
      #pragma unroll
      for (int j=0;j<8;j++) acc[i][j] += a[i]*b[j];
  }
  if (blockIdx.y==0 && tid < 128){
    int row = tid, gr = rbase+row;
    if (gr < NN){
      #pragma unroll
      for (int h=0;h<HH;h++){
        float a=0.f, b=0.f;
        for (int k=0;k<K;k++){
          float xv = xT[k*PITCH+row];
          a += xv*avp[h*K+k];
          b += xv*avp[HH*K+h*K+k];
        }
        si[(size_t)gr*HH+h]=a;
        sj[(size_t)gr*HH+h]=b;
      }
    }
  }
  #pragma unroll
  for (int i=0;i<8;i++){
    int n = rbase + r0 + i;
    if (n < NN){
      uint4 o;
      o.x = (unsigned)f2bf(acc[i][0]) | ((unsigned)f2bf(acc[i][1])<<16);
      o.y = (unsigned)f2bf(acc[i][2]) | ((unsigned)f2bf(acc[i][3])<<16);
      o.z = (unsigned)f2bf(acc[i][4]) | ((unsigned)f2bf(acc[i][5])<<16);
      o.w = (unsigned)f2bf(acc[i][6]) | ((unsigned)f2bf(acc[i][7])<<16);
      *(uint4*)(hout + (size_t)n*NCOL + cbase + c0) = o;
    }
  }
}

// ---------------- slot-order edge pass: exp(lrelu(score)) + per-head sum ----
// R16-proven: FULL grid (NN/4 blocks), one node per wave. Atomics spread
// over 16 bucket-lines per head (blockIdx&15). erec read NT (single-touch
// stream). prec[slot] = {p 4x fp16, src, pad} 16B coalesced write (HH==4);
// {p f32, src} 8B for HH==1. zred summed from UNQUANTIZED f32 p.
template<int HH>
__global__ __launch_bounds__(256)
void k_edge2(const uv4* __restrict__ erec, const int* __restrict__ fill,
             const float* __restrict__ We, const float* __restrict__ si,
             const float* __restrict__ sj, unsigned* __restrict__ prec,
             float* __restrict__ zred){
  int wave = threadIdx.x>>6, lane = threadIdx.x&63;
  int n = blockIdx.x*4 + wave;           // NN % 4 == 0
  float z[HH];
  #pragma unroll
  for (int h=0;h<HH;h++) z[h]=0.f;
  int cnt = 1 + fill[n];
  if (lane < cnt){
    int slot = n*STRIDE + lane;
    uv4 r = ntload(&erec[slot]);
    int s = (int)r.x;
    float eax=h2f((unsigned short)(r.y&0xFFFFu)), eay=h2f((unsigned short)(r.y>>16));
    float eaz=h2f((unsigned short)(r.z&0xFFFFu)), eaw=h2f((unsigned short)(r.z>>16));
    if constexpr (HH==4){
      float4 siv = ((const float4*)si)[n];
      float4 sjv = ((const float4*)sj)[s];
      float te[4] = {siv.x+sjv.x, siv.y+sjv.y, siv.z+sjv.z, siv.w+sjv.w};
      float pv[4];
      #pragma unroll
      for (int h=0;h<4;h++){
        float t = te[h] + eax*We[h*EFEAT+0] + eay*We[h*EFEAT+1]
                        + eaz*We[h*EFEAT+2] + eaw*We[h*EFEAT+3];
        t = (t>0.f)? t : 0.2f*t;
        float p = expf(t);
        z[h]=p; pv[h]=p;
      }
      uv4 o; o.x=f2h2(pv[0],pv[1]); o.y=f2h2(pv[2],pv[3]); o.z=(unsigned)s; o.w=0u;
      ((uv4*)prec)[slot] = o;
    } else {
      float t = si[n] + sj[s]
              + eax*We[0] + eay*We[1] + eaz*We[2] + eaw*We[3];
      t = (t>0.f)? t : 0.2f*t;
      float p = expf(t);
      z[0]=p;
      uv2 o; o.x=__float_as_uint(p); o.y=(unsigned)s;
      ((uv2*)prec)[slot] = o;
    }
  }
  __shared__ float zs[4][HH];
  #pragma unroll
  for (int h=0;h<HH;h++){
    float v=z[h];
    #pragma unroll
    for (int off=32; off>0; off>>=1) v += __shfl_xor(v,off,64);
    if (lane==0) zs[wave][h]=v;
  }
  __syncthreads();
  if (threadIdx.x < HH){
    float tot = zs[0][threadIdx.x]+zs[1][threadIdx.x]
              + zs[2][threadIdx.x]+zs[3][threadIdx.x];
    // head h bucket (blockIdx&15): own 64B line
    atomicAdd(&zred[threadIdx.x*256 + (blockIdx.x&(ZB-1))*16], tot);
  }
}

// ---------------- pull-mode aggregation, wave-per-node, bf16 gather --------
// R20-proven (HH=4 layers): 8-deep unroll, VGPR 32, per-block LDS zt
// finalize by wave 0 in the prologue (one 64-lane load + shfl-reduce,
// zfin[4] in LDS, epilogue broadcast read). Plain (non-NT) prec loads.
template<int HH,int CC,bool DO_ELU>
__global__ __launch_bounds__(256)
void k_agg(const unsigned short* __restrict__ hb, const unsigned* __restrict__ prec,
           const float* __restrict__ zred, const int* __restrict__ fill,
           float* __restrict__ outp){
  constexpr int HC = HH*CC;
  constexpr int V  = HC/64;
  using LT = typename ldt<V>::T;
  int wave = threadIdx.x>>6, lane = threadIdx.x&63;
  int n = blockIdx.x*4 + wave;           // NN % 4 == 0
  int hd = (lane*V)/CC;
  int hw = hd>>1, hs = (hd&1)*16;        // fp16 select within prec record
  __shared__ float zfin[4];
  if (threadIdx.x < 64){
    float zv = zred[(threadIdx.x>>4)*256 + (threadIdx.x&15)*16];
    #pragma unroll
    for (int off=1; off<16; off<<=1) zv += __shfl_xor(zv, off, 64);
    if ((threadIdx.x&15)==0) zfin[threadIdx.x>>4] = zv;
  }
  __syncthreads();
  float acc[V];
  #pragma unroll
  for (int v=0;v<V;v++) acc[v]=0.f;
  auto mac = [&](float p, LT h){
    if constexpr (V==4){
      acc[0] += p*bfl(h.x); acc[1] += p*bfh(h.x);
      acc[2] += p*bfl(h.y); acc[3] += p*bfh(h.y);
    } else {
      acc[0] += p*bfl(h);   acc[1] += p*bfh(h);
    }
  };
  auto ldrec = [&](int idx, int& sr, float& p){
    if constexpr (HH==4){
      uint4 q = ((const uint4*)prec)[idx];
      sr = (int)q.z;
      unsigned wd = hw ? q.y : q.x;
      p = h2f((unsigned short)(wd>>hs));
    } else {
      uint2 q = ((const uint2*)prec)[idx];
      p = __uint_as_float(q.x);
      sr = (int)q.y;
    }
  };
  int beg = n*STRIDE, end = beg + 1 + fill[n];
  int i = beg;
  for (; i+8<=end; i+=8){
    int sr[8]; float p[8]; LT h[8];
    #pragma unroll
    for (int k=0;k<8;k++) ldrec(i+k, sr[k], p[k]);
    #pragma unroll
    for (int k=0;k<8;k++) h[k]=((const LT*)(hb + (size_t)sr[k]*HC))[lane];
    #pragma unroll
    for (int k=0;k<8;k++) mac(p[k], h[k]);
  }
  for (; i<end; i++){
    int sr; float p;
    ldrec(i, sr, p);
    LT h = ((const LT*)(hb + (size_t)sr*HC))[lane];
    mac(p, h);
  }
  float invZ = 1.0f/zfin[hd];
  #pragma unroll
  for (int v=0;v<V;v++) acc[v] *= invZ;
  if constexpr (HH==4){
    #pragma unroll
    for (int off=16; off<64; off<<=1){
      #pragma unroll
      for (int v=0;v<V;v++) acc[v] += __shfl_xor(acc[v], off, 64);
    }
    if (lane < 16){
      float4 o;
      o.x=0.25f*acc[0]; o.y=0.25f*acc[1]; o.z=0.25f*acc[2]; o.w=0.25f*acc[3];
      if (DO_ELU){
        o.x = (o.x>0.f)? o.x : expm1f(o.x);
        o.y = (o.y>0.f)? o.y : expm1f(o.y);
        o.z = (o.z>0.f)? o.z : expm1f(o.z);
        o.w = (o.w>0.f)? o.w : expm1f(o.w);
      }
      ((float4*)outp)[(size_t)n*(CC/4)+lane] = o;
    }
  } else {
    float2 o; o.x=acc[0]; o.y=acc[1];
    if (DO_ELU){
      o.x = (o.x>0.f)? o.x : expm1f(o.x);
      o.y = (o.y>0.f)? o.y : expm1f(o.y);
    }
    ((float2*)outp)[(size_t)n*(CC/2)+lane] = o;
  }
}

// ---------------- R21: XCD-sliced final-layer aggregation (HH=1) ----------
// The HH=1 layer has NO cross-head mean and NO ELU -> each 64B column slice
// of the 256B h-row can be aggregated independently. Slice s = blockIdx&3;
// under the round-robin block->XCD dispatch heuristic, slice s lands on
// XCDs {s, s+4}, so each XCD's L2 only ever touches hbuf bytes
// [s*64,(s+1)*64) of every row = 12.8MB/4 = 3.2MB < 4MB L2 -> gathers
// become L2 hits instead of L3 (k_agg FETCH was 8 XCDs x full table).
// Mapping-conjecture downside is bounded: if blocks don't map %8, footprint
// reverts to today's L3-resident regime (~no change). 16-lane group per
// node: 16 lanes x 4B = exactly one 64B line per gather; prec record (8B)
// is a broadcast within the group; 4 independent edge chains per wave give
// the MLP that the 8-deep unroll gave the unsliced kernel. prec re-read x4
// is L3-absorbed (51MB buffer, L3-resident).
__global__ __launch_bounds__(256)
void k_agg_s1(const unsigned short* __restrict__ hb, const unsigned* __restrict__ prec,
              const float* __restrict__ zred, const int* __restrict__ fill,
              float* __restrict__ outp){
  int tid = threadIdx.x;
  int s = blockIdx.x & 3;               // column slice (64B of 256B row)
  int g = blockIdx.x >> 2;              // node group
  int grp = tid >> 4, sl = tid & 15;    // 16 groups x 16 lanes
  int n = g*16 + grp;                   // NN % 16 == 0
  __shared__ float zf;
  if (tid < 16){
    float zv = zred[tid*16];
    #pragma unroll
    for (int off=1; off<16; off<<=1) zv += __shfl_xor(zv, off, 64);
    if (tid==0) zf = zv;
  }
  __syncthreads();
  float a0=0.f, a1=0.f;
  const unsigned short* hrow_base = hb + s*32 + sl*2;
  int beg = n*STRIDE, end = beg + 1 + fill[n];
  for (int i=beg; i<end; i++){
    uint2 q = ((const uint2*)prec)[i];   // broadcast within 16-lane group
    float p = __uint_as_float(q.x);
    int sr = (int)q.y;
    unsigned h = *(const unsigned*)(hrow_base + (size_t)sr*128);
    a0 += p*bfl(h); a1 += p*bfh(h);
  }
  float invZ = 1.0f/zf;
  float2 o; o.x=a0*invZ; o.y=a1*invZ;   // no ELU on final output
  ((float2*)outp)[(size_t)n*64 + s*16 + sl] = o;
}

extern "C" void kernel_launch(void* const* d_in, const int* in_sizes, int n_in,
                              void* d_out, int out_size, void* d_ws, size_t ws_size,
                              hipStream_t stream){
  const float* x    = (const float*)d_in[0];
  const int*   ei   = (const int*)d_in[1];
  const float* eatt = (const float*)d_in[2];
  const int*   jt   = (const int*)d_in[3];
  const float* emb  = (const float*)d_in[4];
  const float* W0   = (const float*)d_in[5];
  const float* as0  = (const float*)d_in[6];
  const float* ad0  = (const float*)d_in[7];
  const float* We0  = (const float*)d_in[8];
  const float* W1   = (const float*)d_in[9];
  const float* as1  = (const float*)d_in[10];
  const float* ad1  = (const float*)d_in[11];
  const float* We1  = (const float*)d_in[12];
  const float* W2   = (const float*)d_in[13];
  const float* as2  = (const float*)d_in[14];
  const float* ad2  = (const float*)d_in[15];
  const float* We2  = (const float*)d_in[16];
  float* out = (float*)d_out;

  char* p = (char*)d_ws;
  auto alloc = [&](size_t bytes)->char*{
    char* r = p; p += (bytes + 255) & ~(size_t)255; return r;
  };
  unsigned short* hbuf = (unsigned short*)alloc((size_t)NN*256*2); // 25.6 MB bf16
  float* x1     = (float*)alloc((size_t)NN*64*4);
  float* x2     = (float*)alloc((size_t)NN*64*4);
  float* si     = (float*)alloc((size_t)NN*4*4);
  float* sj     = (float*)alloc((size_t)NN*4*4);
  unsigned* prec= (unsigned*)alloc((size_t)NN*STRIDE*16); // 51.2 MB {p fp16x4, src}
  int*   fill   = (int*)alloc((size_t)NN*4);
  uv4*   erec   = (uv4*)alloc((size_t)NN*STRIDE*16);      // 51.2 MB {src, ea fp16x4}
  float* av0    = (float*)alloc(512*4);
  float* av1    = (float*)alloc(512*4);
  float* av2    = (float*)alloc(512*4);
  float* zred   = (float*)alloc(3*1024*4); // 3 layers x 4 heads x 16 buckets x 64B

  // k_av3 blocks 0-2: av + zred zero; blocks 3..: fill zero (precedes k_scatter)
  k_av3    <<<dim3(3+(NN+255)/256), 256, 0, stream>>>(W0,as0,ad0,av0, W1,as1,ad1,av1,
                                                      W2,as2,ad2,av2, zred, fill);
  k_scatter<<<dim3((EEN+255)/256),  256, 0, stream>>>(ei, (const float4*)eatt,
                                                      fill, erec);

  dim3 gg01((NN+127)/128, 2);
  dim3 gg2 ((NN+127)/128, 1);
  dim3 ngrid(NN/4);
  dim3 sgrid((NN/16)*4);   // sliced final agg: node-groups x 4 slices

  // layer 0: concat(x, emb[jt]) -> [N,4,64]
  k_gemm<IN0,256,4,true> <<<gg01, 256, 0, stream>>>(x, jt, emb, W0, av0, hbuf, si, sj);
  k_edge2<4>             <<<ngrid,256, 0, stream>>>(erec, fill, We0, si, sj, prec, zred+0);
  k_agg<4,64,true>       <<<ngrid,256, 0, stream>>>(hbuf, prec, zred+0, fill, x1);

  // layer 1: 64 -> [N,4,64]
  k_gemm<64,256,4,false> <<<gg01, 256, 0, stream>>>(x1, jt, emb, W1, av1, hbuf, si, sj);
  k_edge2<4>             <<<ngrid,256, 0, stream>>>(erec, fill, We1, si, sj, prec, zred+1024);
  k_agg<4,64,true>       <<<ngrid,256, 0, stream>>>(hbuf, prec, zred+1024, fill, x2);

  // layer 2: 64 -> [N,1,128], no ELU on final output; XCD-sliced agg
  k_gemm<64,128,1,false> <<<gg2,  256, 0, stream>>>(x2, jt, emb, W2, av2, hbuf, si, sj);
  k_edge2<1>             <<<ngrid,256, 0, stream>>>(erec, fill, We2, si, sj, prec, zred+2048);
  k_agg_s1               <<<sgrid,256, 0, stream>>>(hbuf, prec, zred+2048, fill, out);
}

// Round 19
// 492.068 us; speedup vs baseline: 1.0863x; 1.0863x over previous
//
#include <hip/hip_runtime.h>
#include <math.h>

#define NN 50000
#define EE 800000
#define EEN (EE+NN)          // edges + self loops
#define STRIDE 64            // fixed CSR stride: self + up to 63 in-edges
#define NFEAT 4
#define EFEAT 4
#define EMBD 16
#define IN0 20   // NF + EMB
#define HIDD 64
#define OUTD 128
#define ZB 16                // zred buckets per head (atomic spread)

// bf16 helpers: storage = unsigned short, RTN-even pack, shift-decode
__device__ __forceinline__ unsigned short f2bf(float f){
  unsigned u = __float_as_uint(f);
  return (unsigned short)((u + 0x7FFFu + ((u>>16)&1u)) >> 16);
}
__device__ __forceinline__ float bfl(unsigned u){ return __uint_as_float(u<<16); }
__device__ __forceinline__ float bfh(unsigned u){ return __uint_as_float(u & 0xFFFF0000u); }

// fp16 helpers (RNE via _Float16 cast). fp16 is SAFE for p (max ~1e5 < 65504,
// R12 measured absmax identical to f32-p). fp8 is NOT (p tails > 448 -> NaN
// from unclamped v_cvt_pk_fp8_f32; R14 failure).
__device__ __forceinline__ unsigned f2h2(float a, float b){
  _Float16 ha=(_Float16)a, hb=(_Float16)b;
  unsigned short ua=*(unsigned short*)&ha, ub=*(unsigned short*)&hb;
  return (unsigned)ua | ((unsigned)ub<<16);
}
__device__ __forceinline__ float h2f(unsigned short u){
  _Float16 h=*(_Float16*)&u; return (float)h;
}

// ext_vector types for nontemporal builtins (HIP uint4 is a struct, not ok)
typedef unsigned uv4 __attribute__((ext_vector_type(4)));
typedef unsigned uv2 __attribute__((ext_vector_type(2)));
template<typename T>
__device__ __forceinline__ T ntload(const T* p){
  return __builtin_nontemporal_load(const_cast<T*>(p));
}

template<int V> struct ldt;
template<> struct ldt<4>{ using T = uint2; };
template<> struct ldt<2>{ using T = unsigned int; };

// ---------------- av (all 3 layers) + zred init + fill zero, one launch ----
template<int F_IN,int HH,int CC>
__device__ __forceinline__ void av_one(const float* W, const float* asrc,
                                       const float* adst, float* av, int tid){
  if (tid >= HH*F_IN) return;
  int h = tid / F_IN, f = tid % F_IN;
  float s1=0.f, s2=0.f;
  for (int c=0;c<CC;c++){
    float wv = W[(size_t)(h*CC+c)*F_IN+f];
    s1 += asrc[h*CC+c]*wv;
    s2 += adst[h*CC+c]*wv;
  }
  av[tid] = s1;
  av[HH*F_IN+tid] = s2;
}
// zred layout: per layer, 4 heads x 16 buckets x 16 floats — each bucket on
// its OWN 64B line. 50k atomics / 64 lines = 781/line ~ 2.3us at the
// measured ~3ns/op same-line rate, overlapped under k_edge2.
// Layer l head h bucket b at zred[l*1024 + h*256 + b*16].
__global__ void k_av3(const float* W0, const float* as0, const float* ad0, float* av0,
                      const float* W1, const float* as1, const float* ad1, float* av1,
                      const float* W2, const float* as2, const float* ad2, float* av2,
                      float* zred, int* fill){
  int b = blockIdx.x, tid = threadIdx.x;
  if (b < 3){
    for (int i=tid; i<1024; i+=256) zred[b*1024+i]=0.f;
    if      (b==0) av_one<IN0,4,64> (W0, as0, ad0, av0, tid);
    else if (b==1) av_one<64,4,64>  (W1, as1, ad1, av1, tid);
    else           av_one<64,1,128> (W2, as2, ad2, av2, tid);
  } else {
    int i=(b-3)*256+tid; if (i<NN) fill[i]=0;
  }
}

// ---------------- fixed-stride CSR scatter, 16B packed records ----------
// erec[slot] = {src, eattr(4x fp16), pad}: ONE 16B random store to ONE line
// per edge. Self loop at slot n*64: {src=n, ea=0}.
__global__ void k_scatter(const int* __restrict__ ei, const float4* __restrict__ eattr,
                          int* fill, uv4* __restrict__ erec){
  int idx = blockIdx.x*blockDim.x + threadIdx.x;
  if (idx < EE){
    int d = ei[EE+idx];
    int s = ei[idx];
    float4 ea = eattr[idx];
    int pos = atomicAdd(&fill[d],1);
    int slot = d*STRIDE + 1 + pos;
    uv4 r; r.x=(unsigned)s; r.y=f2h2(ea.x,ea.y); r.z=f2h2(ea.z,ea.w); r.w=0u;
    erec[slot]=r;
  } else if (idx < EEN){
    int n = idx-EE;
    uv4 r; r.x=(unsigned)n; r.y=0u; r.z=0u; r.w=0u;
    erec[n*STRIDE]=r;
  }
}

// ---------------- outer-product register-tiled GEMM + fused scores --------
template<int K,int NCOL,int HH,bool CONCAT>
__global__ __launch_bounds__(256)
void k_gemm(const float* __restrict__ xin, const int* __restrict__ jt,
            const float* __restrict__ emb, const float* __restrict__ W,
            const float* __restrict__ avp, unsigned short* __restrict__ hout,
            float* __restrict__ si, float* __restrict__ sj){
  constexpr int PITCH = 132;
  __shared__ float xT[K*PITCH];
  __shared__ float wT[K*PITCH];
  __shared__ float EMBL[CONCAT ? 17*EMBD : 1];
  int tid = threadIdx.x;
  int rbase = blockIdx.x*128, cbase = blockIdx.y*128;
  if (CONCAT){
    for (int i=tid; i<17*EMBD; i+=256) EMBL[i]=emb[i];
    __syncthreads();
    if (tid < 128){
      int row = tid;
      int gr = rbase+row; if (gr >= NN) gr = NN-1;
      float4 v = ((const float4*)xin)[gr];
      xT[0*PITCH+row]=v.x; xT[1*PITCH+row]=v.y;
      xT[2*PITCH+row]=v.z; xT[3*PITCH+row]=v.w;
      int j = jt[gr];
      #pragma unroll
      for (int k=0;k<EMBD;k++) xT[(NFEAT+k)*PITCH+row] = EMBL[j*EMBD+k];
    } else {
      int col = tid-128;
      const float4* wp = (const float4*)(W + (size_t)(cbase+col)*K);
      #pragma unroll
      for (int k4=0;k4<K/4;k4++){
        float4 v = wp[k4];
        wT[(4*k4+0)*PITCH+col]=v.x; wT[(4*k4+1)*PITCH+col]=v.y;
        wT[(4*k4+2)*PITCH+col]=v.z; wT[(4*k4+3)*PITCH+col]=v.w;
      }
    }
  } else {
    constexpr int K4 = K/4;
    for (int i=tid; i<128*K4; i+=256){
      int row = i/K4, k4 = i%K4;
      int gr = rbase+row; if (gr >= NN) gr = NN-1;
      float4 v = ((const float4*)xin)[(size_t)gr*K4 + k4];
      xT[(4*k4+0)*PITCH+row]=v.x; xT[(4*k4+1)*PITCH+row]=v.y;
      xT[(4*k4+2)*PITCH+row]=v.z; xT[(4*k4+3)*PITCH+row]=v.w;
    }
    for (int i=tid; i<128*K4; i+=256){
      int col = i/K4, k4 = i%K4;
      float4 v = ((const float4*)W)[(size_t)(cbase+col)*K4 + k4];
      wT[(4*k4+0)*PITCH+col]=v.x; wT[(4*k4+1)*PITCH+col]=v.y;
      wT[(4*k4+2)*PITCH+col]=v.z; wT[(4*k4+3)*PITCH+col]=v.w;
    }
  }
  __syncthreads();
  int lane = tid & 63, w = tid >> 6;
  int r0 = (w>>1)*64 + (lane&7)*8;
  int c0 = (w&1)*64 + (lane>>3)*8;
  float acc[8][8];
  #pragma unroll
  for (int i=0;i<8;i++)
    #pragma unroll
    for (int j=0;j<8;j++) acc[i][j]=0.f;
  #pragma unroll 4
  for (int k=0;k<K;k++){
    float a[8], b[8];
    *(float4*)&a[0] = *(const float4*)&xT[k*PITCH + r0];
    *(float4*)&a[4] = *(const float4*)&xT[k*PITCH + r0 + 4];
    *(float4*)&b[0] = *(const float4*)&wT[k*PITCH + c0];
    *(float4*)&b[4] = *(const float4*)&wT[k*PITCH + c0 + 4];
    #pragma unroll
    for (int i=0;i<8;i++)
      #pragma unroll
      for (int j=0;j<8;j++) acc[i][j] += a[i]*b[j];
  }
  if (blockIdx.y==0 && tid < 128){
    int row = tid, gr = rbase+row;
    if (gr < NN){
      #pragma unroll
      for (int h=0;h<HH;h++){
        float a=0.f, b=0.f;
        for (int k=0;k<K;k++){
          float xv = xT[k*PITCH+row];
          a += xv*avp[h*K+k];
          b += xv*avp[HH*K+h*K+k];
        }
        si[(size_t)gr*HH+h]=a;
        sj[(size_t)gr*HH+h]=b;
      }
    }
  }
  #pragma unroll
  for (int i=0;i<8;i++){
    int n = rbase + r0 + i;
    if (n < NN){
      uint4 o;
      o.x = (unsigned)f2bf(acc[i][0]) | ((unsigned)f2bf(acc[i][1])<<16);
      o.y = (unsigned)f2bf(acc[i][2]) | ((unsigned)f2bf(acc[i][3])<<16);
      o.z = (unsigned)f2bf(acc[i][4]) | ((unsigned)f2bf(acc[i][5])<<16);
      o.w = (unsigned)f2bf(acc[i][6]) | ((unsigned)f2bf(acc[i][7])<<16);
      *(uint4*)(hout + (size_t)n*NCOL + cbase + c0) = o;
    }
  }
}

// ---------------- slot-order edge pass: exp(lrelu(score)) + per-head sum ----
// R16-proven: FULL grid (NN/4 blocks), one node per wave. Atomics spread
// over 16 bucket-lines per head (blockIdx&15). erec read NT (single-touch
// stream). prec[slot] = {p 4x fp16, src, pad} 16B coalesced write (HH==4);
// {p f32, src} 8B for HH==1. zred summed from UNQUANTIZED f32 p.
template<int HH>
__global__ __launch_bounds__(256)
void k_edge2(const uv4* __restrict__ erec, const int* __restrict__ fill,
             const float* __restrict__ We, const float* __restrict__ si,
             const float* __restrict__ sj, unsigned* __restrict__ prec,
             float* __restrict__ zred){
  int wave = threadIdx.x>>6, lane = threadIdx.x&63;
  int n = blockIdx.x*4 + wave;           // NN % 4 == 0
  float z[HH];
  #pragma unroll
  for (int h=0;h<HH;h++) z[h]=0.f;
  int cnt = 1 + fill[n];
  if (lane < cnt){
    int slot = n*STRIDE + lane;
    uv4 r = ntload(&erec[slot]);
    int s = (int)r.x;
    float eax=h2f((unsigned short)(r.y&0xFFFFu)), eay=h2f((unsigned short)(r.y>>16));
    float eaz=h2f((unsigned short)(r.z&0xFFFFu)), eaw=h2f((unsigned short)(r.z>>16));
    if constexpr (HH==4){
      float4 siv = ((const float4*)si)[n];
      float4 sjv = ((const float4*)sj)[s];
      float te[4] = {siv.x+sjv.x, siv.y+sjv.y, siv.z+sjv.z, siv.w+sjv.w};
      float pv[4];
      #pragma unroll
      for (int h=0;h<4;h++){
        float t = te[h] + eax*We[h*EFEAT+0] + eay*We[h*EFEAT+1]
                        + eaz*We[h*EFEAT+2] + eaw*We[h*EFEAT+3];
        t = (t>0.f)? t : 0.2f*t;
        float p = expf(t);
        z[h]=p; pv[h]=p;
      }
      uv4 o; o.x=f2h2(pv[0],pv[1]); o.y=f2h2(pv[2],pv[3]); o.z=(unsigned)s; o.w=0u;
      ((uv4*)prec)[slot] = o;
    } else {
      float t = si[n] + sj[s]
              + eax*We[0] + eay*We[1] + eaz*We[2] + eaw*We[3];
      t = (t>0.f)? t : 0.2f*t;
      float p = expf(t);
      z[0]=p;
      uv2 o; o.x=__float_as_uint(p); o.y=(unsigned)s;
      ((uv2*)prec)[slot] = o;
    }
  }
  __shared__ float zs[4][HH];
  #pragma unroll
  for (int h=0;h<HH;h++){
    float v=z[h];
    #pragma unroll
    for (int off=32; off>0; off>>=1) v += __shfl_xor(v,off,64);
    if (lane==0) zs[wave][h]=v;
  }
  __syncthreads();
  if (threadIdx.x < HH){
    float tot = zs[0][threadIdx.x]+zs[1][threadIdx.x]
              + zs[2][threadIdx.x]+zs[3][threadIdx.x];
    // head h bucket (blockIdx&15): own 64B line
    atomicAdd(&zred[threadIdx.x*256 + (blockIdx.x&(ZB-1))*16], tot);
  }
}

// ---------------- pull-mode aggregation, wave-per-node, bf16 gather --------
// R20-proven (HH=4 layers): 8-deep unroll, VGPR 32, per-block LDS zt
// finalize by wave 0 in the prologue (one 64-lane load + shfl-reduce,
// zfin[4] in LDS, epilogue broadcast read). Plain (non-NT) prec loads.
template<int HH,int CC,bool DO_ELU>
__global__ __launch_bounds__(256)
void k_agg(const unsigned short* __restrict__ hb, const unsigned* __restrict__ prec,
           const float* __restrict__ zred, const int* __restrict__ fill,
           float* __restrict__ outp){
  constexpr int HC = HH*CC;
  constexpr int V  = HC/64;
  using LT = typename ldt<V>::T;
  int wave = threadIdx.x>>6, lane = threadIdx.x&63;
  int n = blockIdx.x*4 + wave;           // NN % 4 == 0
  int hd = (lane*V)/CC;
  int hw = hd>>1, hs = (hd&1)*16;        // fp16 select within prec record
  __shared__ float zfin[4];
  if (threadIdx.x < 64){
    float zv = zred[(threadIdx.x>>4)*256 + (threadIdx.x&15)*16];
    #pragma unroll
    for (int off=1; off<16; off<<=1) zv += __shfl_xor(zv, off, 64);
    if ((threadIdx.x&15)==0) zfin[threadIdx.x>>4] = zv;
  }
  __syncthreads();
  float acc[V];
  #pragma unroll
  for (int v=0;v<V;v++) acc[v]=0.f;
  auto mac = [&](float p, LT h){
    if constexpr (V==4){
      acc[0] += p*bfl(h.x); acc[1] += p*bfh(h.x);
      acc[2] += p*bfl(h.y); acc[3] += p*bfh(h.y);
    } else {
      acc[0] += p*bfl(h);   acc[1] += p*bfh(h);
    }
  };
  auto ldrec = [&](int idx, int& sr, float& p){
    if constexpr (HH==4){
      uint4 q = ((const uint4*)prec)[idx];
      sr = (int)q.z;
      unsigned wd = hw ? q.y : q.x;
      p = h2f((unsigned short)(wd>>hs));
    } else {
      uint2 q = ((const uint2*)prec)[idx];
      p = __uint_as_float(q.x);
      sr = (int)q.y;
    }
  };
  int beg = n*STRIDE, end = beg + 1 + fill[n];
  int i = beg;
  for (; i+8<=end; i+=8){
    int sr[8]; float p[8]; LT h[8];
    #pragma unroll
    for (int k=0;k<8;k++) ldrec(i+k, sr[k], p[k]);
    #pragma unroll
    for (int k=0;k<8;k++) h[k]=((const LT*)(hb + (size_t)sr[k]*HC))[lane];
    #pragma unroll
    for (int k=0;k<8;k++) mac(p[k], h[k]);
  }
  for (; i<end; i++){
    int sr; float p;
    ldrec(i, sr, p);
    LT h = ((const LT*)(hb + (size_t)sr*HC))[lane];
    mac(p, h);
  }
  float invZ = 1.0f/zfin[hd];
  #pragma unroll
  for (int v=0;v<V;v++) acc[v] *= invZ;
  if constexpr (HH==4){
    #pragma unroll
    for (int off=16; off<64; off<<=1){
      #pragma unroll
      for (int v=0;v<V;v++) acc[v] += __shfl_xor(acc[v], off, 64);
    }
    if (lane < 16){
      float4 o;
      o.x=0.25f*acc[0]; o.y=0.25f*acc[1]; o.z=0.25f*acc[2]; o.w=0.25f*acc[3];
      if (DO_ELU){
        o.x = (o.x>0.f)? o.x : expm1f(o.x);
        o.y = (o.y>0.f)? o.y : expm1f(o.y);
        o.z = (o.z>0.f)? o.z : expm1f(o.z);
        o.w = (o.w>0.f)? o.w : expm1f(o.w);
      }
      ((float4*)outp)[(size_t)n*(CC/4)+lane] = o;
    }
  } else {
    float2 o; o.x=acc[0]; o.y=acc[1];
    if (DO_ELU){
      o.x = (o.x>0.f)? o.x : expm1f(o.x);
      o.y = (o.y>0.f)? o.y : expm1f(o.y);
    }
    ((float2*)outp)[(size_t)n*(CC/2)+lane] = o;
  }
}

// ---------------- R22: XCD-sliced final-layer aggregation, 8-deep MLP ----
// R21 counters: slicing CONFIRMED the traffic win (FETCH 190->125MB) but I
// dropped the unroll -> serial dep chain (VALUBusy 19%, MLP=1) = 103us.
// R22 restores the proven 8-deep unroll inside the sliced structure:
// 8 prec records (broadcast within 16-lane group), 8 independent 4B
// gathers in flight, then 8 fmacs. VGPR ~34 (the band k_agg runs 66% occ).
// Roofline: 125MB at k_agg's ~3TB/s = ~42us floor. If >68us next round
// reverts final layer to plain k_agg (R20 = 475.6us known).
__global__ __launch_bounds__(256)
void k_agg_s1(const unsigned short* __restrict__ hb, const unsigned* __restrict__ prec,
              const float* __restrict__ zred, const int* __restrict__ fill,
              float* __restrict__ outp){
  int tid = threadIdx.x;
  int s = blockIdx.x & 3;               // column slice (64B of 256B row)
  int g = blockIdx.x >> 2;              // node group
  int grp = tid >> 4, sl = tid & 15;    // 16 groups x 16 lanes
  int n = g*16 + grp;                   // NN % 16 == 0
  __shared__ float zf;
  if (tid < 16){
    float zv = zred[tid*16];
    #pragma unroll
    for (int off=1; off<16; off<<=1) zv += __shfl_xor(zv, off, 64);
    if (tid==0) zf = zv;
  }
  __syncthreads();
  float a0=0.f, a1=0.f;
  const unsigned short* hrow_base = hb + s*32 + sl*2;
  int beg = n*STRIDE, end = beg + 1 + fill[n];
  int i = beg;
  for (; i+8<=end; i+=8){
    float p[8]; int sr[8]; unsigned h[8];
    #pragma unroll
    for (int k=0;k<8;k++){
      uint2 q = ((const uint2*)prec)[i+k];   // broadcast within group
      p[k] = __uint_as_float(q.x);
      sr[k] = (int)q.y;
    }
    #pragma unroll
    for (int k=0;k<8;k++) h[k] = *(const unsigned*)(hrow_base + (size_t)sr[k]*128);
    #pragma unroll
    for (int k=0;k<8;k++){ a0 += p[k]*bfl(h[k]); a1 += p[k]*bfh(h[k]); }
  }
  for (; i<end; i++){
    uint2 q = ((const uint2*)prec)[i];
    float p = __uint_as_float(q.x);
    int sr = (int)q.y;
    unsigned h = *(const unsigned*)(hrow_base + (size_t)sr*128);
    a0 += p*bfl(h); a1 += p*bfh(h);
  }
  float invZ = 1.0f/zf;
  float2 o; o.x=a0*invZ; o.y=a1*invZ;   // no ELU on final output
  ((float2*)outp)[(size_t)n*64 + s*16 + sl] = o;
}

extern "C" void kernel_launch(void* const* d_in, const int* in_sizes, int n_in,
                              void* d_out, int out_size, void* d_ws, size_t ws_size,
                              hipStream_t stream){
  const float* x    = (const float*)d_in[0];
  const int*   ei   = (const int*)d_in[1];
  const float* eatt = (const float*)d_in[2];
  const int*   jt   = (const int*)d_in[3];
  const float* emb  = (const float*)d_in[4];
  const float* W0   = (const float*)d_in[5];
  const float* as0  = (const float*)d_in[6];
  const float* ad0  = (const float*)d_in[7];
  const float* We0  = (const float*)d_in[8];
  const float* W1   = (const float*)d_in[9];
  const float* as1  = (const float*)d_in[10];
  const float* ad1  = (const float*)d_in[11];
  const float* We1  = (const float*)d_in[12];
  const float* W2   = (const float*)d_in[13];
  const float* as2  = (const float*)d_in[14];
  const float* ad2  = (const float*)d_in[15];
  const float* We2  = (const float*)d_in[16];
  float* out = (float*)d_out;

  char* p = (char*)d_ws;
  auto alloc = [&](size_t bytes)->char*{
    char* r = p; p += (bytes + 255) & ~(size_t)255; return r;
  };
  unsigned short* hbuf = (unsigned short*)alloc((size_t)NN*256*2); // 25.6 MB bf16
  float* x1     = (float*)alloc((size_t)NN*64*4);
  float* x2     = (float*)alloc((size_t)NN*64*4);
  float* si     = (float*)alloc((size_t)NN*4*4);
  float* sj     = (float*)alloc((size_t)NN*4*4);
  unsigned* prec= (unsigned*)alloc((size_t)NN*STRIDE*16); // 51.2 MB {p fp16x4, src}
  int*   fill   = (int*)alloc((size_t)NN*4);
  uv4*   erec   = (uv4*)alloc((size_t)NN*STRIDE*16);      // 51.2 MB {src, ea fp16x4}
  float* av0    = (float*)alloc(512*4);
  float* av1    = (float*)alloc(512*4);
  float* av2    = (float*)alloc(512*4);
  float* zred   = (float*)alloc(3*1024*4); // 3 layers x 4 heads x 16 buckets x 64B

  // k_av3 blocks 0-2: av + zred zero; blocks 3..: fill zero (precedes k_scatter)
  k_av3    <<<dim3(3+(NN+255)/256), 256, 0, stream>>>(W0,as0,ad0,av0, W1,as1,ad1,av1,
                                                      W2,as2,ad2,av2, zred, fill);
  k_scatter<<<dim3((EEN+255)/256),  256, 0, stream>>>(ei, (const float4*)eatt,
                                                      fill, erec);

  dim3 gg01((NN+127)/128, 2);
  dim3 gg2 ((NN+127)/128, 1);
  dim3 ngrid(NN/4);
  dim3 sgrid((NN/16)*4);   // sliced final agg: node-groups x 4 slices

  // layer 0: concat(x, emb[jt]) -> [N,4,64]
  k_gemm<IN0,256,4,true> <<<gg01, 256, 0, stream>>>(x, jt, emb, W0, av0, hbuf, si, sj);
  k_edge2<4>             <<<ngrid,256, 0, stream>>>(erec, fill, We0, si, sj, prec, zred+0);
  k_agg<4,64,true>       <<<ngrid,256, 0, stream>>>(hbuf, prec, zred+0, fill, x1);

  // layer 1: 64 -> [N,4,64]
  k_gemm<64,256,4,false> <<<gg01, 256, 0, stream>>>(x1, jt, emb, W1, av1, hbuf, si, sj);
  k_edge2<4>             <<<ngrid,256, 0, stream>>>(erec, fill, We1, si, sj, prec, zred+1024);
  k_agg<4,64,true>       <<<ngrid,256, 0, stream>>>(hbuf, prec, zred+1024, fill, x2);

  // layer 2: 64 -> [N,1,128], no ELU on final output; XCD-sliced agg
  k_gemm<64,128,1,false> <<<gg2,  256, 0, stream>>>(x2, jt, emb, W2, av2, hbuf, si, sj);
  k_edge2<1>             <<<ngrid,256, 0, stream>>>(erec, fill, We2, si, sj, prec, zred+2048);
  k_agg_s1               <<<sgrid,256, 0, stream>>>(hbuf, prec, zred+2048, fill, out);
}

// Round 20
// 473.568 us; speedup vs baseline: 1.1288x; 1.0391x over previous
//
#include <hip/hip_runtime.h>
#include <math.h>

#define NN 50000
#define EE 800000
#define EEN (EE+NN)          // edges + self loops
#define STRIDE 64            // fixed CSR stride: self + up to 63 in-edges
#define NFEAT 4
#define EFEAT 4
#define EMBD 16
#define IN0 20   // NF + EMB
#define HIDD 64
#define OUTD 128
#define ZB 16                // zred buckets per head (atomic spread)

// bf16 helpers: storage = unsigned short, RTN-even pack, shift-decode
__device__ __forceinline__ unsigned short f2bf(float f){
  unsigned u = __float_as_uint(f);
  return (unsigned short)((u + 0x7FFFu + ((u>>16)&1u)) >> 16);
}
__device__ __forceinline__ float bfl(unsigned u){ return __uint_as_float(u<<16); }
__device__ __forceinline__ float bfh(unsigned u){ return __uint_as_float(u & 0xFFFF0000u); }

// fp16 helpers (RNE via _Float16 cast). fp16 is SAFE for p (max ~1e5 < 65504,
// R12 measured absmax identical to f32-p). fp8 is NOT (p tails > 448 -> NaN
// from unclamped v_cvt_pk_fp8_f32; R14 failure).
__device__ __forceinline__ unsigned f2h2(float a, float b){
  _Float16 ha=(_Float16)a, hb=(_Float16)b;
  unsigned short ua=*(unsigned short*)&ha, ub=*(unsigned short*)&hb;
  return (unsigned)ua | ((unsigned)ub<<16);
}
__device__ __forceinline__ float h2f(unsigned short u){
  _Float16 h=*(_Float16*)&u; return (float)h;
}

// ext_vector types for nontemporal builtins (HIP uint4 is a struct, not ok)
typedef unsigned uv4 __attribute__((ext_vector_type(4)));
typedef unsigned uv2 __attribute__((ext_vector_type(2)));
template<typename T>
__device__ __forceinline__ T ntload(const T* p){
  return __builtin_nontemporal_load(const_cast<T*>(p));
}

template<int V> struct ldt;
template<> struct ldt<4>{ using T = uint2; };
template<> struct ldt<2>{ using T = unsigned int; };

// ---------------- av (all 3 layers) + zred init + fill zero, one launch ----
template<int F_IN,int HH,int CC>
__device__ __forceinline__ void av_one(const float* W, const float* asrc,
                                       const float* adst, float* av, int tid){
  if (tid >= HH*F_IN) return;
  int h = tid / F_IN, f = tid % F_IN;
  float s1=0.f, s2=0.f;
  for (int c=0;c<CC;c++){
    float wv = W[(size_t)(h*CC+c)*F_IN+f];
    s1 += asrc[h*CC+c]*wv;
    s2 += adst[h*CC+c]*wv;
  }
  av[tid] = s1;
  av[HH*F_IN+tid] = s2;
}
// zred layout: per layer, 4 heads x 16 buckets x 16 floats — each bucket on
// its OWN 64B line. 50k atomics / 64 lines = 781/line ~ 2.3us at the
// measured ~3ns/op same-line rate, overlapped under k_edge2.
// Layer l head h bucket b at zred[l*1024 + h*256 + b*16].
__global__ void k_av3(const float* W0, const float* as0, const float* ad0, float* av0,
                      const float* W1, const float* as1, const float* ad1, float* av1,
                      const float* W2, const float* as2, const float* ad2, float* av2,
                      float* zred, int* fill){
  int b = blockIdx.x, tid = threadIdx.x;
  if (b < 3){
    for (int i=tid; i<1024; i+=256) zred[b*1024+i]=0.f;
    if      (b==0) av_one<IN0,4,64> (W0, as0, ad0, av0, tid);
    else if (b==1) av_one<64,4,64>  (W1, as1, ad1, av1, tid);
    else           av_one<64,1,128> (W2, as2, ad2, av2, tid);
  } else {
    int i=(b-3)*256+tid; if (i<NN) fill[i]=0;
  }
}

// ---------------- fixed-stride CSR scatter, 16B packed records ----------
// erec[slot] = {src, eattr(4x fp16), pad}: ONE 16B random store to ONE line
// per edge. Self loop at slot n*64: {src=n, ea=0}.
__global__ void k_scatter(const int* __restrict__ ei, const float4* __restrict__ eattr,
                          int* fill, uv4* __restrict__ erec){
  int idx = blockIdx.x*blockDim.x + threadIdx.x;
  if (idx < EE){
    int d = ei[EE+idx];
    int s = ei[idx];
    float4 ea = eattr[idx];
    int pos = atomicAdd(&fill[d],1);
    int slot = d*STRIDE + 1 + pos;
    uv4 r; r.x=(unsigned)s; r.y=f2h2(ea.x,ea.y); r.z=f2h2(ea.z,ea.w); r.w=0u;
    erec[slot]=r;
  } else if (idx < EEN){
    int n = idx-EE;
    uv4 r; r.x=(unsigned)n; r.y=0u; r.z=0u; r.w=0u;
    erec[n*STRIDE]=r;
  }
}

// ---------------- outer-product register-tiled GEMM + fused scores --------
template<int K,int NCOL,int HH,bool CONCAT>
__global__ __launch_bounds__(256)
void k_gemm(const float* __restrict__ xin, const int* __restrict__ jt,
            const float* __restrict__ emb, const float* __restrict__ W,
            const float* __restrict__ avp, unsigned short* __restrict__ hout,
            float* __restrict__ si, float* __restrict__ sj){
  constexpr int PITCH = 132;
  __shared__ float xT[K*PITCH];
  __shared__ float wT[K*PITCH];
  __shared__ float EMBL[CONCAT ? 17*EMBD : 1];
  int tid = threadIdx.x;
  int rbase = blockIdx.x*128, cbase = blockIdx.y*128;
  if (CONCAT){
    for (int i=tid; i<17*EMBD; i+=256) EMBL[i]=emb[i];
    __syncthreads();
    if (tid < 128){
      int row = tid;
      int gr = rbase+row; if (gr >= NN) gr = NN-1;
      float4 v = ((const float4*)xin)[gr];
      xT[0*PITCH+row]=v.x; xT[1*PITCH+row]=v.y;
      xT[2*PITCH+row]=v.z; xT[3*PITCH+row]=v.w;
      int j = jt[gr];
      #pragma unroll
      for (int k=0;k<EMBD;k++) xT[(NFEAT+k)*PITCH+row] = EMBL[j*EMBD+k];
    } else {
      int col = tid-128;
      const float4* wp = (const float4*)(W + (size_t)(cbase+col)*K);
      #pragma unroll
      for (int k4=0;k4<K/4;k4++){
        float4 v = wp[k4];
        wT[(4*k4+0)*PITCH+col]=v.x; wT[(4*k4+1)*PITCH+col]=v.y;
        wT[(4*k4+2)*PITCH+col]=v.z; wT[(4*k4+3)*PITCH+col]=v.w;
      }
    }
  } else {
    constexpr int K4 = K/4;
    for (int i=tid; i<128*K4; i+=256){
      int row = i/K4, k4 = i%K4;
      int gr = rbase+row; if (gr >= NN) gr = NN-1;
      float4 v = ((const float4*)xin)[(size_t)gr*K4 + k4];
      xT[(4*k4+0)*PITCH+row]=v.x; xT[(4*k4+1)*PITCH+row]=v.y;
      xT[(4*k4+2)*PITCH+row]=v.z; xT[(4*k4+3)*PITCH+row]=v.w;
    }
    for (int i=tid; i<128*K4; i+=256){
      int col = i/K4, k4 = i%K4;
      float4 v = ((const float4*)W)[(size_t)(cbase+col)*K4 + k4];
      wT[(4*k4+0)*PITCH+col]=v.x; wT[(4*k4+1)*PITCH+col]=v.y;
      wT[(4*k4+2)*PITCH+col]=v.z; wT[(4*k4+3)*PITCH+col]=v.w;
    }
  }
  __syncthreads();
  int lane = tid & 63, w = tid >> 6;
  int r0 = (w>>1)*64 + (lane&7)*8;
  int c0 = (w&1)*64 + (lane>>3)*8;
  float acc[8][8];
  #pragma unroll
  for (int i=0;i<8;i++)
    #pragma unroll
    for (int j=0;j<8;j++) acc[i][j]=0.f;
  #pragma unroll 4
  for (int k=0;k<K;k++){
    float a[8], b[8];
    *(float4*)&a[0] = *(const float4*)&xT[k*PITCH + r0];
    *(float4*)&a[4] = *(const float4*)&xT[k*PITCH + r0 + 4];
    *(float4*)&b[0] = *(const float4*)&wT[k*PITCH + c0];
    *(float4*)&b[4] = *(const float4*)&wT[k*PITCH + c0 + 4];
    #pragma unroll
    for (int i=0;i<8;i++)
      #pragma unroll
      for (int j=0;j<8;j++) acc[i][j] += a[i]*b[j];
  }
  if (blockIdx.y==0 && tid < 128){
    int row = tid, gr = rbase+row;
    if (gr < NN){
      #pragma unroll
      for (int h=0;h<HH;h++){
        float a=0.f, b=0.f;
        for (int k=0;k<K;k++){
          float xv = xT[k*PITCH+row];
          a += xv*avp[h*K+k];
          b += xv*avp[HH*K+h*K+k];
        }
        si[(size_t)gr*HH+h]=a;
        sj[(size_t)gr*HH+h]=b;
      }
    }
  }
  #pragma unroll
  for (int i=0;i<8;i++){
    int n = rbase + r0 + i;
    if (n < NN){
      uint4 o;
      o.x = (unsigned)f2bf(acc[i][0]) | ((unsigned)f2bf(acc[i][1])<<16);
      o.y = (unsigned)f2bf(acc[i][2]) | ((unsigned)f2bf(acc[i][3])<<16);
      o.z = (unsigned)f2bf(acc[i][4]) | ((unsigned)f2bf(acc[i][5])<<16);
      o.w = (unsigned)f2bf(acc[i][6]) | ((unsigned)f2bf(acc[i][7])<<16);
      *(uint4*)(hout + (size_t)n*NCOL + cbase + c0) = o;
    }
  }
}

// ---------------- slot-order edge pass: exp(lrelu(score)) + per-head sum ----
// R16-proven: FULL grid (NN/4 blocks), one node per wave. Atomics spread
// over 16 bucket-lines per head (blockIdx&15). erec read NT (single-touch
// stream). prec[slot] = {p 4x fp16, src, pad} 16B coalesced write (HH==4);
// {p f32, src} 8B for HH==1. zred summed from UNQUANTIZED f32 p.
template<int HH>
__global__ __launch_bounds__(256)
void k_edge2(const uv4* __restrict__ erec, const int* __restrict__ fill,
             const float* __restrict__ We, const float* __restrict__ si,
             const float* __restrict__ sj, unsigned* __restrict__ prec,
             float* __restrict__ zred){
  int wave = threadIdx.x>>6, lane = threadIdx.x&63;
  int n = blockIdx.x*4 + wave;           // NN % 4 == 0
  float z[HH];
  #pragma unroll
  for (int h=0;h<HH;h++) z[h]=0.f;
  int cnt = 1 + fill[n];
  if (lane < cnt){
    int slot = n*STRIDE + lane;
    uv4 r = ntload(&erec[slot]);
    int s = (int)r.x;
    float eax=h2f((unsigned short)(r.y&0xFFFFu)), eay=h2f((unsigned short)(r.y>>16));
    float eaz=h2f((unsigned short)(r.z&0xFFFFu)), eaw=h2f((unsigned short)(r.z>>16));
    if constexpr (HH==4){
      float4 siv = ((const float4*)si)[n];
      float4 sjv = ((const float4*)sj)[s];
      float te[4] = {siv.x+sjv.x, siv.y+sjv.y, siv.z+sjv.z, siv.w+sjv.w};
      float pv[4];
      #pragma unroll
      for (int h=0;h<4;h++){
        float t = te[h] + eax*We[h*EFEAT+0] + eay*We[h*EFEAT+1]
                        + eaz*We[h*EFEAT+2] + eaw*We[h*EFEAT+3];
        t = (t>0.f)? t : 0.2f*t;
        float p = expf(t);
        z[h]=p; pv[h]=p;
      }
      uv4 o; o.x=f2h2(pv[0],pv[1]); o.y=f2h2(pv[2],pv[3]); o.z=(unsigned)s; o.w=0u;
      ((uv4*)prec)[slot] = o;
    } else {
      float t = si[n] + sj[s]
              + eax*We[0] + eay*We[1] + eaz*We[2] + eaw*We[3];
      t = (t>0.f)? t : 0.2f*t;
      float p = expf(t);
      z[0]=p;
      uv2 o; o.x=__float_as_uint(p); o.y=(unsigned)s;
      ((uv2*)prec)[slot] = o;
    }
  }
  __shared__ float zs[4][HH];
  #pragma unroll
  for (int h=0;h<HH;h++){
    float v=z[h];
    #pragma unroll
    for (int off=32; off>0; off>>=1) v += __shfl_xor(v,off,64);
    if (lane==0) zs[wave][h]=v;
  }
  __syncthreads();
  if (threadIdx.x < HH){
    float tot = zs[0][threadIdx.x]+zs[1][threadIdx.x]
              + zs[2][threadIdx.x]+zs[3][threadIdx.x];
    // head h bucket (blockIdx&15): own 64B line
    atomicAdd(&zred[threadIdx.x*256 + (blockIdx.x&(ZB-1))*16], tot);
  }
}

// ---------------- pull-mode aggregation, wave-per-node, bf16 gather --------
// R20-proven (best measured, all 3 layers): 8-deep unroll, VGPR 32, per-
// block LDS zt finalize by wave 0 in the prologue (one 64-lane load +
// shfl-reduce, zfin[4] in LDS, epilogue broadcast read). Plain (non-NT)
// prec loads. R21/R22 slicing experiments REVERTED: blockIdx->XCD pinning
// is unreliable (R21 FETCH 125MB not ~30MB ideal; both rounds lost to this
// version), and the gather has never exceeded ~3.1 TB/s L2-miss traffic
// across 10 structural variants — treat as the fabric ceiling.
template<int HH,int CC,bool DO_ELU>
__global__ __launch_bounds__(256)
void k_agg(const unsigned short* __restrict__ hb, const unsigned* __restrict__ prec,
           const float* __restrict__ zred, const int* __restrict__ fill,
           float* __restrict__ outp){
  constexpr int HC = HH*CC;
  constexpr int V  = HC/64;
  using LT = typename ldt<V>::T;
  int wave = threadIdx.x>>6, lane = threadIdx.x&63;
  int n = blockIdx.x*4 + wave;           // NN % 4 == 0
  int hd = (lane*V)/CC;
  int hw = hd>>1, hs = (hd&1)*16;        // fp16 select within prec record
  __shared__ float zfin[4];
  if (threadIdx.x < 64){
    float zv = zred[(threadIdx.x>>4)*256 + (threadIdx.x&15)*16];
    #pragma unroll
    for (int off=1; off<16; off<<=1) zv += __shfl_xor(zv, off, 64);
    if ((threadIdx.x&15)==0) zfin[threadIdx.x>>4] = zv;
  }
  __syncthreads();
  float acc[V];
  #pragma unroll
  for (int v=0;v<V;v++) acc[v]=0.f;
  auto mac = [&](float p, LT h){
    if constexpr (V==4){
      acc[0] += p*bfl(h.x); acc[1] += p*bfh(h.x);
      acc[2] += p*bfl(h.y); acc[3] += p*bfh(h.y);
    } else {
      acc[0] += p*bfl(h);   acc[1] += p*bfh(h);
    }
  };
  auto ldrec = [&](int idx, int& sr, float& p){
    if constexpr (HH==4){
      uint4 q = ((const uint4*)prec)[idx];
      sr = (int)q.z;
      unsigned wd = hw ? q.y : q.x;
      p = h2f((unsigned short)(wd>>hs));
    } else {
      uint2 q = ((const uint2*)prec)[idx];
      p = __uint_as_float(q.x);
      sr = (int)q.y;
    }
  };
  int beg = n*STRIDE, end = beg + 1 + fill[n];
  int i = beg;
  for (; i+8<=end; i+=8){
    int sr[8]; float p[8]; LT h[8];
    #pragma unroll
    for (int k=0;k<8;k++) ldrec(i+k, sr[k], p[k]);
    #pragma unroll
    for (int k=0;k<8;k++) h[k]=((const LT*)(hb + (size_t)sr[k]*HC))[lane];
    #pragma unroll
    for (int k=0;k<8;k++) mac(p[k], h[k]);
  }
  for (; i<end; i++){
    int sr; float p;
    ldrec(i, sr, p);
    LT h = ((const LT*)(hb + (size_t)sr*HC))[lane];
    mac(p, h);
  }
  float invZ = 1.0f/zfin[hd];
  #pragma unroll
  for (int v=0;v<V;v++) acc[v] *= invZ;
  if constexpr (HH==4){
    #pragma unroll
    for (int off=16; off<64; off<<=1){
      #pragma unroll
      for (int v=0;v<V;v++) acc[v] += __shfl_xor(acc[v], off, 64);
    }
    if (lane < 16){
      float4 o;
      o.x=0.25f*acc[0]; o.y=0.25f*acc[1]; o.z=0.25f*acc[2]; o.w=0.25f*acc[3];
      if (DO_ELU){
        o.x = (o.x>0.f)? o.x : expm1f(o.x);
        o.y = (o.y>0.f)? o.y : expm1f(o.y);
        o.z = (o.z>0.f)? o.z : expm1f(o.z);
        o.w = (o.w>0.f)? o.w : expm1f(o.w);
      }
      ((float4*)outp)[(size_t)n*(CC/4)+lane] = o;
    }
  } else {
    float2 o; o.x=acc[0]; o.y=acc[1];
    if (DO_ELU){
      o.x = (o.x>0.f)? o.x : expm1f(o.x);
      o.y = (o.y>0.f)? o.y : expm1f(o.y);
    }
    ((float2*)outp)[(size_t)n*(CC/2)+lane] = o;
  }
}

extern "C" void kernel_launch(void* const* d_in, const int* in_sizes, int n_in,
                              void* d_out, int out_size, void* d_ws, size_t ws_size,
                              hipStream_t stream){
  const float* x    = (const float*)d_in[0];
  const int*   ei   = (const int*)d_in[1];
  const float* eatt = (const float*)d_in[2];
  const int*   jt   = (const int*)d_in[3];
  const float* emb  = (const float*)d_in[4];
  const float* W0   = (const float*)d_in[5];
  const float* as0  = (const float*)d_in[6];
  const float* ad0  = (const float*)d_in[7];
  const float* We0  = (const float*)d_in[8];
  const float* W1   = (const float*)d_in[9];
  const float* as1  = (const float*)d_in[10];
  const float* ad1  = (const float*)d_in[11];
  const float* We1  = (const float*)d_in[12];
  const float* W2   = (const float*)d_in[13];
  const float* as2  = (const float*)d_in[14];
  const float* ad2  = (const float*)d_in[15];
  const float* We2  = (const float*)d_in[16];
  float* out = (float*)d_out;

  char* p = (char*)d_ws;
  auto alloc = [&](size_t bytes)->char*{
    char* r = p; p += (bytes + 255) & ~(size_t)255; return r;
  };
  unsigned short* hbuf = (unsigned short*)alloc((size_t)NN*256*2); // 25.6 MB bf16
  float* x1     = (float*)alloc((size_t)NN*64*4);
  float* x2     = (float*)alloc((size_t)NN*64*4);
  float* si     = (float*)alloc((size_t)NN*4*4);
  float* sj     = (float*)alloc((size_t)NN*4*4);
  unsigned* prec= (unsigned*)alloc((size_t)NN*STRIDE*16); // 51.2 MB {p fp16x4, src}
  int*   fill   = (int*)alloc((size_t)NN*4);
  uv4*   erec   = (uv4*)alloc((size_t)NN*STRIDE*16);      // 51.2 MB {src, ea fp16x4}
  float* av0    = (float*)alloc(512*4);
  float* av1    = (float*)alloc(512*4);
  float* av2    = (float*)alloc(512*4);
  float* zred   = (float*)alloc(3*1024*4); // 3 layers x 4 heads x 16 buckets x 64B

  // k_av3 blocks 0-2: av + zred zero; blocks 3..: fill zero (precedes k_scatter)
  k_av3    <<<dim3(3+(NN+255)/256), 256, 0, stream>>>(W0,as0,ad0,av0, W1,as1,ad1,av1,
                                                      W2,as2,ad2,av2, zred, fill);
  k_scatter<<<dim3((EEN+255)/256),  256, 0, stream>>>(ei, (const float4*)eatt,
                                                      fill, erec);

  dim3 gg01((NN+127)/128, 2);
  dim3 gg2 ((NN+127)/128, 1);
  dim3 ngrid(NN/4);

  // layer 0: concat(x, emb[jt]) -> [N,4,64]
  k_gemm<IN0,256,4,true> <<<gg01, 256, 0, stream>>>(x, jt, emb, W0, av0, hbuf, si, sj);
  k_edge2<4>             <<<ngrid,256, 0, stream>>>(erec, fill, We0, si, sj, prec, zred+0);
  k_agg<4,64,true>       <<<ngrid,256, 0, stream>>>(hbuf, prec, zred+0, fill, x1);

  // layer 1: 64 -> [N,4,64]
  k_gemm<64,256,4,false> <<<gg01, 256, 0, stream>>>(x1, jt, emb, W1, av1, hbuf, si, sj);
  k_edge2<4>             <<<ngrid,256, 0, stream>>>(erec, fill, We1, si, sj, prec, zred+1024);
  k_agg<4,64,true>       <<<ngrid,256, 0, stream>>>(hbuf, prec, zred+1024, fill, x2);

  // layer 2: 64 -> [N,1,128], no ELU on final output
  k_gemm<64,128,1,false> <<<gg2,  256, 0, stream>>>(x2, jt, emb, W2, av2, hbuf, si, sj);
  k_edge2<1>             <<<ngrid,256, 0, stream>>>(erec, fill, We2, si, sj, prec, zred+2048);
  k_agg<1,128,false>     <<<ngrid,256, 0, stream>>>(hbuf, prec, zred+2048, fill, out);
}